// Round 4
// baseline (6086.608 us; speedup 1.0000x reference)
//
#include <hip/hip_runtime.h>
#include <math.h>

#define NB 16384
#define NT 10
#define CHM_R 8192
#define CHM_S 4096

typedef _Float16 f16;
typedef f16 f16x8 __attribute__((ext_vector_type(8)));
typedef f16 f16x4 __attribute__((ext_vector_type(4)));
typedef float f32x4 __attribute__((ext_vector_type(4)));

__device__ __forceinline__ float sigm(float v) { return 1.0f / (1.0f + expf(-v)); }

__device__ __forceinline__ void load8f(const f16* p, float* d) {
    f16x8 v = *(const f16x8*)p;
    #pragma unroll
    for (int i = 0; i < 8; ++i) d[i] = (float)v[i];
}
__device__ __forceinline__ void load8f(const float* p, float* d) {
    float4 a = *(const float4*)p;
    float4 b = *(const float4*)(p + 4);
    d[0] = a.x; d[1] = a.y; d[2] = a.z; d[3] = a.w;
    d[4] = b.x; d[5] = b.y; d[6] = b.z; d[7] = b.w;
}

// ---------------- h0 = tanh(feats @ W_in^T + b_in), output split fp16 ----------------
__global__ __launch_bounds__(256) void h0_kernel(
    const float* __restrict__ x, const float* __restrict__ W,
    const float* __restrict__ bias, f16* __restrict__ h_hi, f16* __restrict__ h_lo)
{
    __shared__ __align__(16) float As[32][128];
    __shared__ __align__(16) float Ws[32][64];
    const int t = threadIdx.x;
    const int tx = t & 15, ty = t >> 4;
    const int mBase = blockIdx.x * 128, nBase = blockIdx.y * 64;
    const int kq = (t & 7) * 4, r8 = t >> 3;

    float4 acc[8];
    #pragma unroll
    for (int mi = 0; mi < 8; ++mi) acc[mi] = make_float4(0.f, 0.f, 0.f, 0.f);

    const float* aPtr = x + (size_t)(mBase + r8) * 272 + 16 + kq;
    const float* wPtr = W + (size_t)(nBase + r8) * 256 + kq;

    for (int kb = 0; kb < 8; ++kb) {
        const int k0 = kb * 32;
        __syncthreads();
        #pragma unroll
        for (int i = 0; i < 4; ++i) {
            float4 v = *(const float4*)(aPtr + (size_t)(i * 32) * 272 + k0);
            const int row = r8 + i * 32;
            const float vv[4] = {v.x, v.y, v.z, v.w};
            #pragma unroll
            for (int j = 0; j < 4; ++j) As[kq + j][row ^ ((kq + j) & 28)] = vv[j];
        }
        #pragma unroll
        for (int i = 0; i < 2; ++i) {
            float4 v = *(const float4*)(wPtr + (size_t)(i * 32) * 256 + k0);
            const int row = r8 + i * 32;
            const float vv[4] = {v.x, v.y, v.z, v.w};
            #pragma unroll
            for (int j = 0; j < 4; ++j) Ws[kq + j][row ^ ((kq + j) & 28)] = vv[j];
        }
        __syncthreads();
        #pragma unroll 8
        for (int k = 0; k < 32; ++k) {
            const int s = k & 28;
            float4 a0 = *(const float4*)&As[k][(ty * 8) ^ s];
            float4 a1 = *(const float4*)&As[k][((ty * 8) + 4) ^ s];
            float4 bb = *(const float4*)&Ws[k][(tx * 4) ^ s];
            const float am[8] = {a0.x, a0.y, a0.z, a0.w, a1.x, a1.y, a1.z, a1.w};
            #pragma unroll
            for (int mi = 0; mi < 8; ++mi) {
                acc[mi].x += am[mi] * bb.x; acc[mi].y += am[mi] * bb.y;
                acc[mi].z += am[mi] * bb.z; acc[mi].w += am[mi] * bb.w;
            }
        }
    }
    const int j0 = nBase + tx * 4;
    const int kg = j0 >> 3, jo = j0 & 7;
    const float4 b4 = *(const float4*)&bias[j0];
    #pragma unroll
    for (int mi = 0; mi < 8; ++mi) {
        const int row = mBase + ty * 8 + mi;
        float o[4];
        o[0] = tanhf(acc[mi].x + b4.x); o[1] = tanhf(acc[mi].y + b4.y);
        o[2] = tanhf(acc[mi].z + b4.z); o[3] = tanhf(acc[mi].w + b4.w);
        f16x4 hi4, lo4;
        #pragma unroll
        for (int c = 0; c < 4; ++c) {
            f16 hv = (f16)o[c];
            hi4[c] = hv;
            lo4[c] = (f16)(o[c] - (float)hv);
        }
        *(f16x4*)&h_hi[((size_t)kg * NB + row) * 8 + jo] = hi4;
        *(f16x4*)&h_lo[((size_t)kg * NB + row) * 8 + jo] = lo4;
    }
}

// ---------------- weight split: W (rows x 512) -> hi/lo fp16 in [kg][rows][8] ----------------
__global__ __launch_bounds__(256) void wsplit_kernel(
    const float* __restrict__ W, f16* __restrict__ whi, f16* __restrict__ wlo, int rows)
{
    const int u = blockIdx.x * 256 + threadIdx.x;   // 64*rows
    const int kg = u / rows, row = u - kg * rows;
    const float* s = W + (size_t)row * 512 + kg * 8;
    f16x8 hi8, lo8;
    #pragma unroll
    for (int i = 0; i < 8; ++i) {
        float v = s[i];
        f16 hv = (f16)v;
        hi8[i] = hv;
        lo8[i] = (f16)(v - (float)hv);
    }
    *(f16x8*)&whi[(size_t)u * 8] = hi8;
    *(f16x8*)&wlo[(size_t)u * 8] = lo8;
}

// ---------------- Wih transpose -> [128][1536] fp32 ----------------
__global__ __launch_bounds__(256) void wihT_kernel(
    const float* __restrict__ Wih, float* __restrict__ WihT)
{
    const int u = blockIdx.x * 256 + threadIdx.x;   // 196608 = 128*1536
    const int w = u / 1536, c = u - w * 1536;
    WihT[u] = Wih[(size_t)c * 128 + w];
}

// ---------------- GEMM: gh = h @ Whh^T via fp16 hi/lo split MFMA ----------------
// grid (chm/128, 1536/128), block 256 (4 waves, 2x2 wave grid, wave tile 64x64)
// GT = f16 (receiver) or float (sender, argmax-grade precision)
template <typename GT>
__global__ __launch_bounds__(256) void gemm_split(
    const f16* __restrict__ h_hi, const f16* __restrict__ h_lo,
    const f16* __restrict__ w_hi, const f16* __restrict__ w_lo,
    GT* __restrict__ gh, int rowBase, int chm)
{
    __shared__ __align__(16) f16 lds[2048 * 8];   // Ah | Al | Bh | Bl
    const int t = threadIdx.x;
    const int lane = t & 63;
    const int wave = t >> 6;
    const int wm = wave >> 1, wn = wave & 1;
    const int m0 = rowBase + blockIdx.x * 128;
    const int n0 = blockIdx.y * 128;

    const f32x4 z4 = {0.f, 0.f, 0.f, 0.f};
    f32x4 acc[4][4];
    #pragma unroll
    for (int mi = 0; mi < 4; ++mi)
        #pragma unroll
        for (int ni = 0; ni < 4; ++ni) acc[mi][ni] = z4;

    const int abase = (((lane >> 4) << 7) + wm * 64 + (lane & 15)) * 8;
    const int bbase = (((lane >> 4) << 7) + wn * 64 + (lane & 15)) * 8;

    for (int kb = 0; kb < 16; ++kb) {
        const int kg0 = kb * 4;
        f16x8 st[8];
        #pragma unroll
        for (int i = 0; i < 8; ++i) {
            const int u = i * 256 + t;
            const int kg = kg0 + ((u >> 7) & 3);
            const int row = u & 127;
            const f16* src;
            if ((i >> 1) == 0)      src = h_hi + ((size_t)kg * NB + m0 + row) * 8;
            else if ((i >> 1) == 1) src = h_lo + ((size_t)kg * NB + m0 + row) * 8;
            else if ((i >> 1) == 2) src = w_hi + ((size_t)kg * 1536 + n0 + row) * 8;
            else                    src = w_lo + ((size_t)kg * 1536 + n0 + row) * 8;
            st[i] = *(const f16x8*)src;
        }
        __syncthreads();
        #pragma unroll
        for (int i = 0; i < 8; ++i) *(f16x8*)&lds[(size_t)(i * 256 + t) * 8] = st[i];
        __syncthreads();

        f16x8 ah[4], al[4], bh[4], bl[4];
        #pragma unroll
        for (int mi = 0; mi < 4; ++mi) {
            ah[mi] = *(const f16x8*)&lds[abase + mi * 128];
            al[mi] = *(const f16x8*)&lds[4096 + abase + mi * 128];
        }
        #pragma unroll
        for (int ni = 0; ni < 4; ++ni) {
            bh[ni] = *(const f16x8*)&lds[8192 + bbase + ni * 128];
            bl[ni] = *(const f16x8*)&lds[12288 + bbase + ni * 128];
        }
        #pragma unroll
        for (int mi = 0; mi < 4; ++mi)
            #pragma unroll
            for (int ni = 0; ni < 4; ++ni) {
                acc[mi][ni] = __builtin_amdgcn_mfma_f32_16x16x32_f16(ah[mi], bh[ni], acc[mi][ni], 0, 0, 0);
                acc[mi][ni] = __builtin_amdgcn_mfma_f32_16x16x32_f16(ah[mi], bl[ni], acc[mi][ni], 0, 0, 0);
                acc[mi][ni] = __builtin_amdgcn_mfma_f32_16x16x32_f16(al[mi], bh[ni], acc[mi][ni], 0, 0, 0);
            }
    }

    // epilogue: gh in [cg=col/8][chm][8], rows LOCAL to chunk
    const int colb = n0 + wn * 64 + (lane & 15);
    const int rowb = blockIdx.x * 128 + wm * 64 + ((lane >> 4) << 2);
    #pragma unroll
    for (int mi = 0; mi < 4; ++mi)
        #pragma unroll
        for (int ni = 0; ni < 4; ++ni) {
            const int col = colb + ni * 16;
            #pragma unroll
            for (int j = 0; j < 4; ++j) {
                const int rl = rowb + mi * 16 + j;
                gh[((size_t)(col >> 3) * chm + rl) * 8 + (col & 7)] = (GT)acc[mi][ni][j];
            }
        }
}

// ---------------- GRU update (elementwise), shared sender/receiver ----------------
// grid chm/64, block 256: wave = 64 consecutive rows, q = t>>6 selects kg phase
template <typename GT>
__global__ __launch_bounds__(256) void update_kernel(
    f16* __restrict__ h_hi, f16* __restrict__ h_lo,
    const GT* __restrict__ gh,
    const float* __restrict__ WihT,
    const float* __restrict__ bih, const float* __restrict__ bhh,
    const int* __restrict__ wsel,   // word per row (-1 = zero input), or nullptr
    int rowBase, int flags, int chm) // flags bit0: gh==0, bit1: h==0
{
    const int t = threadIdx.x;
    const int r = t & 63, q = t >> 6;
    const int rowL = blockIdx.x * 64 + r;
    const int row = rowBase + rowL;
    const int word = wsel ? wsel[row] : -1;

    for (int kk = 0; kk < 16; ++kk) {
        const int kg = q + kk * 4;
        const int c0 = kg * 8;
        float gr[8], gz[8], gn[8], hp[8];
        if (!(flags & 1)) {
            load8f(&gh[((size_t)kg * chm + rowL) * 8], gr);
            load8f(&gh[((size_t)(kg + 64) * chm + rowL) * 8], gz);
            load8f(&gh[((size_t)(kg + 128) * chm + rowL) * 8], gn);
        } else {
            #pragma unroll
            for (int i = 0; i < 8; ++i) { gr[i] = 0.f; gz[i] = 0.f; gn[i] = 0.f; }
        }
        if (!(flags & 2)) {
            f16x8 vh = *(const f16x8*)&h_hi[((size_t)kg * NB + row) * 8];
            f16x8 vl = *(const f16x8*)&h_lo[((size_t)kg * NB + row) * 8];
            #pragma unroll
            for (int i = 0; i < 8; ++i) hp[i] = (float)vh[i] + (float)vl[i];
        } else {
            #pragma unroll
            for (int i = 0; i < 8; ++i) hp[i] = 0.f;
        }
        float wir[8], wiz[8], win[8];
        if (word >= 0) {
            const float* wt = WihT + (size_t)word * 1536;
            #pragma unroll
            for (int i = 0; i < 8; ++i) {
                wir[i] = wt[c0 + i];
                wiz[i] = wt[512 + c0 + i];
                win[i] = wt[1024 + c0 + i];
            }
        } else {
            #pragma unroll
            for (int i = 0; i < 8; ++i) { wir[i] = 0.f; wiz[i] = 0.f; win[i] = 0.f; }
        }
        f16x8 oh, ol;
        #pragma unroll
        for (int i = 0; i < 8; ++i) {
            float rr = sigm(wir[i] + bih[c0 + i] + gr[i] + bhh[c0 + i]);
            float zz = sigm(wiz[i] + bih[512 + c0 + i] + gz[i] + bhh[512 + c0 + i]);
            float nn = tanhf(win[i] + bih[1024 + c0 + i] + rr * (gn[i] + bhh[1024 + c0 + i]));
            float hv = (1.f - zz) * nn + zz * hp[i];
            f16 hh = (f16)hv;
            oh[i] = hh;
            ol[i] = (f16)(hv - (float)hh);
        }
        *(f16x8*)&h_hi[((size_t)kg * NB + row) * 8] = oh;
        *(f16x8*)&h_lo[((size_t)kg * NB + row) * 8] = ol;
    }
}

// ---------------- logits = h @ W_sp^T + b_sp + gumbel; word = argmax ----------------
// reads split h; fp32 VALU GEMM. grid (NB/64), block 256
__global__ __launch_bounds__(256) void argmax_split(
    const f16* __restrict__ h_hi, const f16* __restrict__ h_lo,
    const float* __restrict__ Wsp, const float* __restrict__ bsp,
    const float* __restrict__ gum, int* __restrict__ wout)
{
    __shared__ __align__(16) float As[32][64];
    __shared__ __align__(16) float Ws[32][128];
    const int t = threadIdx.x;
    const int tx = t & 31, ty = t >> 5;
    const int mBase = blockIdx.x * 64;
    const int kq = (t & 7) * 4, r8 = t >> 3;
    const int arow = t & 63, akgl = t >> 6;

    float4 acc[8];
    #pragma unroll
    for (int mi = 0; mi < 8; ++mi) acc[mi] = make_float4(0.f, 0.f, 0.f, 0.f);

    const float* wPtr = Wsp + (size_t)r8 * 512 + kq;

    for (int kb = 0; kb < 16; ++kb) {
        const int k0 = kb * 32;
        __syncthreads();
        {
            const int kg = kb * 4 + akgl;
            f16x8 hi8 = *(const f16x8*)&h_hi[((size_t)kg * NB + mBase + arow) * 8];
            f16x8 lo8 = *(const f16x8*)&h_lo[((size_t)kg * NB + mBase + arow) * 8];
            #pragma unroll
            for (int j = 0; j < 8; ++j) {
                const int k = akgl * 8 + j;
                As[k][arow ^ (k & 28)] = (float)hi8[j] + (float)lo8[j];
            }
        }
        #pragma unroll
        for (int i = 0; i < 4; ++i) {
            float4 v = *(const float4*)(wPtr + (size_t)(i * 32) * 512 + k0);
            const int row = r8 + i * 32;
            const float vv[4] = {v.x, v.y, v.z, v.w};
            #pragma unroll
            for (int j = 0; j < 4; ++j) Ws[kq + j][row ^ ((kq + j) & 28)] = vv[j];
        }
        __syncthreads();
        #pragma unroll 8
        for (int k = 0; k < 32; ++k) {
            const int s = k & 28;
            float4 a0 = *(const float4*)&As[k][(ty * 8) ^ s];
            float4 a1 = *(const float4*)&As[k][((ty * 8) + 4) ^ s];
            float4 bb = *(const float4*)&Ws[k][(tx * 4) ^ s];
            const float am[8] = {a0.x, a0.y, a0.z, a0.w, a1.x, a1.y, a1.z, a1.w};
            #pragma unroll
            for (int mi = 0; mi < 8; ++mi) {
                acc[mi].x += am[mi] * bb.x; acc[mi].y += am[mi] * bb.y;
                acc[mi].z += am[mi] * bb.z; acc[mi].w += am[mi] * bb.w;
            }
        }
    }

    const float4 b4 = *(const float4*)&bsp[tx * 4];
    #pragma unroll
    for (int mi = 0; mi < 8; ++mi) {
        const int row = mBase + ty * 8 + mi;
        const float4 g4 = *(const float4*)&gum[(size_t)row * 128 + tx * 4];
        float v[4];
        v[0] = acc[mi].x + b4.x + g4.x; v[1] = acc[mi].y + b4.y + g4.y;
        v[2] = acc[mi].z + b4.z + g4.z; v[3] = acc[mi].w + b4.w + g4.w;
        float bv = v[0]; int bi = tx * 4;
        #pragma unroll
        for (int nj = 1; nj < 4; ++nj) if (v[nj] > bv) { bv = v[nj]; bi = tx * 4 + nj; }
        #pragma unroll
        for (int off = 1; off <= 16; off <<= 1) {
            float ov = __shfl_xor(bv, off, 64);
            int oi = __shfl_xor(bi, off, 64);
            if (ov > bv || (ov == bv && oi < bi)) { bv = ov; bi = oi; }
        }
        if (tx == 0) wout[row] = bi;
    }
}

// ---------------- alive mask -> effective word (-1 = zero input) ----------------
__global__ __launch_bounds__(256) void eff_kernel(
    const int* __restrict__ words, int* __restrict__ eff)
{
    const int b = blockIdx.x * 256 + threadIdx.x;
    int alive = 1;
    #pragma unroll
    for (int t = 0; t < NT; ++t) {
        const int w = words[(size_t)t * NB + b];
        eff[(size_t)t * NB + b] = alive ? w : -1;
        alive = alive & (w != 0);
    }
}

// ---------------- score = [h_n, task] @ W_c^T + b_c ----------------
__global__ __launch_bounds__(256) void score_kernel(
    const f16* __restrict__ h_hi, const f16* __restrict__ h_lo,
    const float* __restrict__ x, const float* __restrict__ Wc,
    const float* __restrict__ bc, float* __restrict__ out)
{
    __shared__ float Wcs[10][528];
    const int t = threadIdx.x;
    for (int q = t; q < 1320; q += 256)
        *(float4*)&(((float*)Wcs)[q * 4]) = *(const float4*)&Wc[q * 4];
    __syncthreads();

    const int row = blockIdx.x * 256 + t;
    float acc[10];
    #pragma unroll
    for (int d = 0; d < 10; ++d) acc[d] = 0.f;

    for (int kg = 0; kg < 64; ++kg) {
        f16x8 vh = *(const f16x8*)&h_hi[((size_t)kg * NB + row) * 8];
        f16x8 vl = *(const f16x8*)&h_lo[((size_t)kg * NB + row) * 8];
        #pragma unroll
        for (int i = 0; i < 8; ++i) {
            const float v = (float)vh[i] + (float)vl[i];
            #pragma unroll
            for (int d = 0; d < 10; ++d) acc[d] += v * Wcs[d][kg * 8 + i];
        }
    }
    #pragma unroll
    for (int j = 0; j < 16; ++j) {
        const float tv = x[(size_t)row * 272 + j];
        #pragma unroll
        for (int d = 0; d < 10; ++d) acc[d] += tv * Wcs[d][512 + j];
    }
    #pragma unroll
    for (int d = 0; d < 10; ++d) out[(size_t)row * 10 + d] = acc[d] + bc[d];
}

extern "C" void kernel_launch(void* const* d_in, const int* in_sizes, int n_in,
                              void* d_out, int out_size, void* d_ws, size_t ws_size,
                              hipStream_t stream) {
    const float* x      = (const float*)d_in[0];
    const float* gumbel = (const float*)d_in[1];
    const float* W_in   = (const float*)d_in[2];
    const float* b_in   = (const float*)d_in[3];
    const float* Wih_s  = (const float*)d_in[4];
    const float* Whh_s  = (const float*)d_in[5];
    const float* bih_s  = (const float*)d_in[6];
    const float* bhh_s  = (const float*)d_in[7];
    const float* W_sp   = (const float*)d_in[8];
    const float* b_sp   = (const float*)d_in[9];
    const float* Wih_r  = (const float*)d_in[10];
    const float* Whh_r  = (const float*)d_in[11];
    const float* bih_r  = (const float*)d_in[12];
    const float* bhh_r  = (const float*)d_in[13];
    const float* W_c    = (const float*)d_in[14];
    const float* b_c    = (const float*)d_in[15];
    float* out = (float*)d_out;

    // workspace map (bytes) — identical footprint to the proven R2/R3 map
    char* base = (char*)d_ws;
    f16* h_hi    = (f16*)(base);                    // 16,777,216
    f16* h_lo    = (f16*)(base + 16777216);         // 16,777,216
    void* ghbuf  = (void*)(base + 33554432);        // 25,165,824 (f16 CHM_R | f32 CHM_S)
    f16* ws_s_hi = (f16*)(base + 58720256);         // 1,572,864
    f16* ws_s_lo = (f16*)(base + 60293120);         // 1,572,864
    f16* ws_r_hi = (f16*)(base + 61865984);         // 1,572,864
    f16* ws_r_lo = (f16*)(base + 63438848);         // 1,572,864
    float* wihT_s = (float*)(base + 65011712);      // 786,432
    float* wihT_r = (float*)(base + 65798144);      // 786,432
    int* words   = (int*)(base + 66584576);         // 655,360
    int* eff     = (int*)(base + 67239936);         // 655,360

    f16* ghh = (f16*)ghbuf;
    float* ghf = (float*)ghbuf;

    const dim3 blk(256);
    const dim3 gGemmS(CHM_S / 128, 1536 / 128);
    const dim3 gGemmR(CHM_R / 128, 1536 / 128);
    const dim3 gUpdS(CHM_S / 64);
    const dim3 gUpdR(CHM_R / 64);

    // ---- weight prep ----
    wsplit_kernel<<<dim3(384), blk, 0, stream>>>(Whh_s, ws_s_hi, ws_s_lo, 1536);
    wsplit_kernel<<<dim3(384), blk, 0, stream>>>(Whh_r, ws_r_hi, ws_r_lo, 1536);
    wihT_kernel<<<dim3(768), blk, 0, stream>>>(Wih_s, wihT_s);
    wihT_kernel<<<dim3(768), blk, 0, stream>>>(Wih_r, wihT_r);

    // ---- h0 (fp32 GEMM, split output) ----
    h0_kernel<<<dim3(NB / 128, 512 / 64), blk, 0, stream>>>(x, W_in, b_in, h_hi, h_lo);

    // ---- sender: 10 steps; split-MFMA GEMM with fp32 gh (argmax-grade) ----
    for (int t = 0; t < NT; ++t) {
        const int* wprev = (t == 0) ? (const int*)nullptr : (words + (size_t)(t - 1) * NB);
        for (int c = 0; c < 4; ++c) {
            gemm_split<float><<<gGemmS, blk, 0, stream>>>(
                h_hi, h_lo, ws_s_hi, ws_s_lo, ghf, c * CHM_S, CHM_S);
            update_kernel<float><<<gUpdS, blk, 0, stream>>>(
                h_hi, h_lo, ghf, wihT_s, bih_s, bhh_s, wprev, c * CHM_S, 0, CHM_S);
        }
        argmax_split<<<dim3(NB / 64), blk, 0, stream>>>(
            h_hi, h_lo, W_sp, b_sp, gumbel + (size_t)t * NB * 128, words + (size_t)t * NB);
    }
    eff_kernel<<<dim3(NB / 256), blk, 0, stream>>>(words, eff);

    // ---- receiver: 10 steps (step 0 from zero state), fp16 gh (proven) ----
    update_kernel<f16><<<gUpdR, blk, 0, stream>>>(h_hi, h_lo, ghh, wihT_r, bih_r, bhh_r, eff, 0, 3, CHM_R);
    update_kernel<f16><<<gUpdR, blk, 0, stream>>>(h_hi, h_lo, ghh, wihT_r, bih_r, bhh_r, eff, CHM_R, 3, CHM_R);
    for (int t = 1; t < NT; ++t) {
        const int* ef = eff + (size_t)t * NB;
        gemm_split<f16><<<gGemmR, blk, 0, stream>>>(h_hi, h_lo, ws_r_hi, ws_r_lo, ghh, 0, CHM_R);
        update_kernel<f16><<<gUpdR, blk, 0, stream>>>(h_hi, h_lo, ghh, wihT_r, bih_r, bhh_r, ef, 0, 0, CHM_R);
        gemm_split<f16><<<gGemmR, blk, 0, stream>>>(h_hi, h_lo, ws_r_hi, ws_r_lo, ghh, CHM_R, CHM_R);
        update_kernel<f16><<<gUpdR, blk, 0, stream>>>(h_hi, h_lo, ghh, wihT_r, bih_r, bhh_r, ef, CHM_R, 0, CHM_R);
    }

    score_kernel<<<dim3(NB / 256), blk, 0, stream>>>(h_hi, h_lo, x, W_c, b_c, out);
}

// Round 5
// 3761.387 us; speedup vs baseline: 1.6182x; 1.6182x over previous
//
#include <hip/hip_runtime.h>
#include <math.h>

#define NB 16384
#define NT 10
#define CHM 8192

typedef _Float16 f16;
typedef f16 f16x8 __attribute__((ext_vector_type(8)));
typedef f16 f16x4 __attribute__((ext_vector_type(4)));
typedef float f32x4 __attribute__((ext_vector_type(4)));

__device__ __forceinline__ float sigm(float v) { return 1.0f / (1.0f + expf(-v)); }

// ---------------- h0 = tanh(feats @ W_in^T + b_in), split fp16 out, one chunk ----------------
// grid (CHM/128, 512/64), block 256. x pre-offset to chunk rows.
__global__ __launch_bounds__(256) void h0_kernel(
    const float* __restrict__ x, const float* __restrict__ W,
    const float* __restrict__ bias, f16* __restrict__ h_hi, f16* __restrict__ h_lo)
{
    __shared__ __align__(16) float As[32][128];
    __shared__ __align__(16) float Ws[32][64];
    const int t = threadIdx.x;
    const int tx = t & 15, ty = t >> 4;
    const int mBase = blockIdx.x * 128, nBase = blockIdx.y * 64;
    const int kq = (t & 7) * 4, r8 = t >> 3;

    float4 acc[8];
    #pragma unroll
    for (int mi = 0; mi < 8; ++mi) acc[mi] = make_float4(0.f, 0.f, 0.f, 0.f);

    const float* aPtr = x + (size_t)(mBase + r8) * 272 + 16 + kq;
    const float* wPtr = W + (size_t)(nBase + r8) * 256 + kq;

    for (int kb = 0; kb < 8; ++kb) {
        const int k0 = kb * 32;
        __syncthreads();
        #pragma unroll
        for (int i = 0; i < 4; ++i) {
            float4 v = *(const float4*)(aPtr + (size_t)(i * 32) * 272 + k0);
            const int row = r8 + i * 32;
            const float vv[4] = {v.x, v.y, v.z, v.w};
            #pragma unroll
            for (int j = 0; j < 4; ++j) As[kq + j][row ^ ((kq + j) & 28)] = vv[j];
        }
        #pragma unroll
        for (int i = 0; i < 2; ++i) {
            float4 v = *(const float4*)(wPtr + (size_t)(i * 32) * 256 + k0);
            const int row = r8 + i * 32;
            const float vv[4] = {v.x, v.y, v.z, v.w};
            #pragma unroll
            for (int j = 0; j < 4; ++j) Ws[kq + j][row ^ ((kq + j) & 28)] = vv[j];
        }
        __syncthreads();
        #pragma unroll 8
        for (int k = 0; k < 32; ++k) {
            const int s = k & 28;
            float4 a0 = *(const float4*)&As[k][(ty * 8) ^ s];
            float4 a1 = *(const float4*)&As[k][((ty * 8) + 4) ^ s];
            float4 bb = *(const float4*)&Ws[k][(tx * 4) ^ s];
            const float am[8] = {a0.x, a0.y, a0.z, a0.w, a1.x, a1.y, a1.z, a1.w};
            #pragma unroll
            for (int mi = 0; mi < 8; ++mi) {
                acc[mi].x += am[mi] * bb.x; acc[mi].y += am[mi] * bb.y;
                acc[mi].z += am[mi] * bb.z; acc[mi].w += am[mi] * bb.w;
            }
        }
    }
    const int j0 = nBase + tx * 4;
    const int kg = j0 >> 3, jo = j0 & 7;
    const float4 b4 = *(const float4*)&bias[j0];
    #pragma unroll
    for (int mi = 0; mi < 8; ++mi) {
        const int row = mBase + ty * 8 + mi;
        float o[4];
        o[0] = tanhf(acc[mi].x + b4.x); o[1] = tanhf(acc[mi].y + b4.y);
        o[2] = tanhf(acc[mi].z + b4.z); o[3] = tanhf(acc[mi].w + b4.w);
        f16x4 hi4, lo4;
        #pragma unroll
        for (int c = 0; c < 4; ++c) {
            f16 hv = (f16)o[c];
            hi4[c] = hv;
            lo4[c] = (f16)(o[c] - (float)hv);
        }
        *(f16x4*)&h_hi[((size_t)kg * CHM + row) * 8 + jo] = hi4;
        *(f16x4*)&h_lo[((size_t)kg * CHM + row) * 8 + jo] = lo4;
    }
}

// ---------------- weight split: W (1536 x 512) -> hi/lo fp16 in [kg][1536][8] ----------------
__global__ __launch_bounds__(256) void wsplit_kernel(
    const float* __restrict__ W, f16* __restrict__ whi, f16* __restrict__ wlo)
{
    const int u = blockIdx.x * 256 + threadIdx.x;   // 98304 = 64*1536
    const int kg = u / 1536, row = u - kg * 1536;
    const float* s = W + (size_t)row * 512 + kg * 8;
    f16x8 hi8, lo8;
    #pragma unroll
    for (int i = 0; i < 8; ++i) {
        float v = s[i];
        f16 hv = (f16)v;
        hi8[i] = hv;
        lo8[i] = (f16)(v - (float)hv);
    }
    *(f16x8*)&whi[(size_t)u * 8] = hi8;
    *(f16x8*)&wlo[(size_t)u * 8] = lo8;
}

// ---------------- Wih transpose -> [128][1536] fp32 ----------------
__global__ __launch_bounds__(256) void wihT_kernel(
    const float* __restrict__ Wih, float* __restrict__ WihT)
{
    const int u = blockIdx.x * 256 + threadIdx.x;   // 196608 = 128*1536
    const int w = u / 1536, c = u - w * 1536;
    WihT[u] = Wih[(size_t)c * 128 + w];
}

// ---------------- fused GRU step: gh GEMM (split MFMA) + gate math, one chunk ----------------
// grid (CHM/128, 512/64) = (64,8), block 256 (4 waves, 2x2; wave tile 64 rows x 32 cols x 3 gates)
// Reads hc (own rows only), writes hn (own rows) -> race-free across n-blocks via chunk rotation.
template <int HZERO>
__global__ __launch_bounds__(256) void fused_gru(
    const f16* __restrict__ hc_hi, const f16* __restrict__ hc_lo,  // cur chunk [64][CHM][8]
    f16* __restrict__ hn_hi, f16* __restrict__ hn_lo,              // next chunk
    const f16* __restrict__ w_hi, const f16* __restrict__ w_lo,    // [64][1536][8]
    const float* __restrict__ WihT,                                 // [128][1536]
    const float* __restrict__ bih, const float* __restrict__ bhh,
    const int* __restrict__ wsel)                                   // pre-offset to chunk, or null
{
    // LDS units of 16B: Ah[4][128] | Al[4][128] | Bh[3][4][64] | Bl[3][4][64] = 2560 units, 40KB
    __shared__ __align__(16) f16 lds[2560 * 8];
    const int t = threadIdx.x;
    const int lane = t & 63, wave = t >> 6;
    const int wm = wave >> 1, wn = wave & 1;
    const int m0 = blockIdx.x * 128;
    const int n0 = blockIdx.y * 64;

    const f32x4 z4 = {0.f, 0.f, 0.f, 0.f};
    f32x4 acc[3][4][2];
    #pragma unroll
    for (int g = 0; g < 3; ++g)
        #pragma unroll
        for (int mi = 0; mi < 4; ++mi)
            #pragma unroll
            for (int ni = 0; ni < 2; ++ni) acc[g][mi][ni] = z4;

    if (!HZERO) {
        const int asel = ((lane >> 4) << 7) + wm * 64 + (lane & 15);
        const int bsel = ((lane >> 4) << 6) + wn * 32 + (lane & 15);
        for (int kb = 0; kb < 16; ++kb) {
            const int kg0 = kb * 4;
            f16x8 st[10];
            #pragma unroll
            for (int i = 0; i < 10; ++i) {
                const int u = i * 256 + t;
                const f16* src;
                if (u < 1024) {
                    const int v = u & 511;
                    const f16* hp = (u < 512) ? hc_hi : hc_lo;
                    src = hp + ((size_t)(kg0 + (v >> 7)) * CHM + m0 + (v & 127)) * 8;
                } else {
                    const int v = u - 1024;
                    const f16* wp = (v < 768) ? w_hi : w_lo;
                    const int w = (v < 768) ? v : v - 768;   // gate*256 + kg*64 + row
                    src = wp + ((size_t)(kg0 + ((w >> 6) & 3)) * 1536 + (w >> 8) * 512 + n0 + (w & 63)) * 8;
                }
                st[i] = *(const f16x8*)src;
            }
            __syncthreads();
            #pragma unroll
            for (int i = 0; i < 10; ++i) *(f16x8*)&lds[(size_t)(i * 256 + t) * 8] = st[i];
            __syncthreads();

            f16x8 ah[4], al[4];
            #pragma unroll
            for (int mi = 0; mi < 4; ++mi) {
                ah[mi] = *(const f16x8*)&lds[(size_t)(asel + mi * 16) * 8];
                al[mi] = *(const f16x8*)&lds[(size_t)(512 + asel + mi * 16) * 8];
            }
            #pragma unroll
            for (int g = 0; g < 3; ++g) {
                f16x8 bh[2], bl[2];
                #pragma unroll
                for (int ni = 0; ni < 2; ++ni) {
                    bh[ni] = *(const f16x8*)&lds[(size_t)(1024 + g * 256 + bsel + ni * 16) * 8];
                    bl[ni] = *(const f16x8*)&lds[(size_t)(1792 + g * 256 + bsel + ni * 16) * 8];
                }
                #pragma unroll
                for (int mi = 0; mi < 4; ++mi)
                    #pragma unroll
                    for (int ni = 0; ni < 2; ++ni) {
                        acc[g][mi][ni] = __builtin_amdgcn_mfma_f32_16x16x32_f16(ah[mi], bh[ni], acc[g][mi][ni], 0, 0, 0);
                        acc[g][mi][ni] = __builtin_amdgcn_mfma_f32_16x16x32_f16(ah[mi], bl[ni], acc[g][mi][ni], 0, 0, 0);
                        acc[g][mi][ni] = __builtin_amdgcn_mfma_f32_16x16x32_f16(al[mi], bh[ni], acc[g][mi][ni], 0, 0, 0);
                    }
            }
        }
    }

    // ---- epilogue: full GRU gate math in-register, write split h_next ----
    const int colb = n0 + wn * 32 + (lane & 15);
    const int rowb = m0 + wm * 64 + ((lane >> 4) << 2);
    int wd[16];
    #pragma unroll
    for (int mi = 0; mi < 4; ++mi)
        #pragma unroll
        for (int j = 0; j < 4; ++j)
            wd[mi * 4 + j] = wsel ? wsel[rowb + mi * 16 + j] : -1;

    #pragma unroll
    for (int ni = 0; ni < 2; ++ni) {
        const int col = colb + ni * 16;
        const float b_r = bih[col], b_z = bih[512 + col], b_n = bih[1024 + col];
        const float c_r = bhh[col], c_z = bhh[512 + col], c_n = bhh[1024 + col];
        const size_t cbase = (size_t)(col >> 3) * CHM * 8 + (col & 7);
        #pragma unroll
        for (int mi = 0; mi < 4; ++mi) {
            #pragma unroll
            for (int j = 0; j < 4; ++j) {
                const int r = rowb + mi * 16 + j;
                const int word = wd[mi * 4 + j];
                float wir = 0.f, wiz = 0.f, win = 0.f;
                if (word >= 0) {
                    const float* wt = WihT + (size_t)word * 1536 + col;
                    wir = wt[0]; wiz = wt[512]; win = wt[1024];
                }
                const size_t idx = cbase + (size_t)r * 8;
                float hold = 0.f;
                if (!HZERO) hold = (float)hc_hi[idx] + (float)hc_lo[idx];
                const float rr = sigm(wir + b_r + acc[0][mi][ni][j] + c_r);
                const float zz = sigm(wiz + b_z + acc[1][mi][ni][j] + c_z);
                const float nn = tanhf(win + b_n + rr * (acc[2][mi][ni][j] + c_n));
                const float hv = (1.f - zz) * nn + zz * hold;
                const f16 hh = (f16)hv;
                hn_hi[idx] = hh;
                hn_lo[idx] = (f16)(hv - (float)hh);
            }
        }
    }
}

// ---------------- logits + gumbel argmax, one chunk ----------------
// grid (CHM/64), block 256. gum/wout pre-offset to chunk.
__global__ __launch_bounds__(256) void argmax_split(
    const f16* __restrict__ h_hi, const f16* __restrict__ h_lo,
    const float* __restrict__ Wsp, const float* __restrict__ bsp,
    const float* __restrict__ gum, int* __restrict__ wout)
{
    __shared__ __align__(16) float As[32][64];
    __shared__ __align__(16) float Ws[32][128];
    const int t = threadIdx.x;
    const int tx = t & 31, ty = t >> 5;
    const int mBase = blockIdx.x * 64;
    const int kq = (t & 7) * 4, r8 = t >> 3;
    const int arow = t & 63, akgl = t >> 6;

    float4 acc[8];
    #pragma unroll
    for (int mi = 0; mi < 8; ++mi) acc[mi] = make_float4(0.f, 0.f, 0.f, 0.f);

    const float* wPtr = Wsp + (size_t)r8 * 512 + kq;

    for (int kb = 0; kb < 16; ++kb) {
        const int k0 = kb * 32;
        __syncthreads();
        {
            const int kg = kb * 4 + akgl;
            f16x8 hi8 = *(const f16x8*)&h_hi[((size_t)kg * CHM + mBase + arow) * 8];
            f16x8 lo8 = *(const f16x8*)&h_lo[((size_t)kg * CHM + mBase + arow) * 8];
            #pragma unroll
            for (int j = 0; j < 8; ++j) {
                const int k = akgl * 8 + j;
                As[k][arow ^ (k & 28)] = (float)hi8[j] + (float)lo8[j];
            }
        }
        #pragma unroll
        for (int i = 0; i < 4; ++i) {
            float4 v = *(const float4*)(wPtr + (size_t)(i * 32) * 512 + k0);
            const int row = r8 + i * 32;
            const float vv[4] = {v.x, v.y, v.z, v.w};
            #pragma unroll
            for (int j = 0; j < 4; ++j) Ws[kq + j][row ^ ((kq + j) & 28)] = vv[j];
        }
        __syncthreads();
        #pragma unroll 8
        for (int k = 0; k < 32; ++k) {
            const int s = k & 28;
            float4 a0 = *(const float4*)&As[k][(ty * 8) ^ s];
            float4 a1 = *(const float4*)&As[k][((ty * 8) + 4) ^ s];
            float4 bb = *(const float4*)&Ws[k][(tx * 4) ^ s];
            const float am[8] = {a0.x, a0.y, a0.z, a0.w, a1.x, a1.y, a1.z, a1.w};
            #pragma unroll
            for (int mi = 0; mi < 8; ++mi) {
                acc[mi].x += am[mi] * bb.x; acc[mi].y += am[mi] * bb.y;
                acc[mi].z += am[mi] * bb.z; acc[mi].w += am[mi] * bb.w;
            }
        }
    }

    const float4 b4 = *(const float4*)&bsp[tx * 4];
    #pragma unroll
    for (int mi = 0; mi < 8; ++mi) {
        const int row = mBase + ty * 8 + mi;
        const float4 g4 = *(const float4*)&gum[(size_t)row * 128 + tx * 4];
        float v[4];
        v[0] = acc[mi].x + b4.x + g4.x; v[1] = acc[mi].y + b4.y + g4.y;
        v[2] = acc[mi].z + b4.z + g4.z; v[3] = acc[mi].w + b4.w + g4.w;
        float bv = v[0]; int bi = tx * 4;
        #pragma unroll
        for (int nj = 1; nj < 4; ++nj) if (v[nj] > bv) { bv = v[nj]; bi = tx * 4 + nj; }
        #pragma unroll
        for (int off = 1; off <= 16; off <<= 1) {
            float ov = __shfl_xor(bv, off, 64);
            int oi = __shfl_xor(bi, off, 64);
            if (ov > bv || (ov == bv && oi < bi)) { bv = ov; bi = oi; }
        }
        if (tx == 0) wout[row] = bi;
    }
}

// ---------------- alive mask -> effective word (-1 = zero input) ----------------
__global__ __launch_bounds__(256) void eff_kernel(
    const int* __restrict__ words, int* __restrict__ eff)
{
    const int b = blockIdx.x * 256 + threadIdx.x;
    int alive = 1;
    #pragma unroll
    for (int t = 0; t < NT; ++t) {
        const int w = words[(size_t)t * NB + b];
        eff[(size_t)t * NB + b] = alive ? w : -1;
        alive = alive & (w != 0);
    }
}

// ---------------- score = [h_n, task] @ W_c^T + b_c, one chunk ----------------
// grid (CHM/256). x/out pre-offset to chunk.
__global__ __launch_bounds__(256) void score_kernel(
    const f16* __restrict__ h_hi, const f16* __restrict__ h_lo,
    const float* __restrict__ x, const float* __restrict__ Wc,
    const float* __restrict__ bc, float* __restrict__ out)
{
    __shared__ float Wcs[10][528];
    const int t = threadIdx.x;
    for (int q = t; q < 1320; q += 256)
        *(float4*)&(((float*)Wcs)[q * 4]) = *(const float4*)&Wc[q * 4];
    __syncthreads();

    const int row = blockIdx.x * 256 + t;
    float acc[10];
    #pragma unroll
    for (int d = 0; d < 10; ++d) acc[d] = 0.f;

    for (int kg = 0; kg < 64; ++kg) {
        f16x8 vh = *(const f16x8*)&h_hi[((size_t)kg * CHM + row) * 8];
        f16x8 vl = *(const f16x8*)&h_lo[((size_t)kg * CHM + row) * 8];
        #pragma unroll
        for (int i = 0; i < 8; ++i) {
            const float v = (float)vh[i] + (float)vl[i];
            #pragma unroll
            for (int d = 0; d < 10; ++d) acc[d] += v * Wcs[d][kg * 8 + i];
        }
    }
    #pragma unroll
    for (int j = 0; j < 16; ++j) {
        const float tv = x[(size_t)row * 272 + j];
        #pragma unroll
        for (int d = 0; d < 10; ++d) acc[d] += tv * Wcs[d][512 + j];
    }
    #pragma unroll
    for (int d = 0; d < 10; ++d) out[(size_t)row * 10 + d] = acc[d] + bc[d];
}

extern "C" void kernel_launch(void* const* d_in, const int* in_sizes, int n_in,
                              void* d_out, int out_size, void* d_ws, size_t ws_size,
                              hipStream_t stream) {
    const float* x      = (const float*)d_in[0];
    const float* gumbel = (const float*)d_in[1];
    const float* W_in   = (const float*)d_in[2];
    const float* b_in   = (const float*)d_in[3];
    const float* Wih_s  = (const float*)d_in[4];
    const float* Whh_s  = (const float*)d_in[5];
    const float* bih_s  = (const float*)d_in[6];
    const float* bhh_s  = (const float*)d_in[7];
    const float* W_sp   = (const float*)d_in[8];
    const float* b_sp   = (const float*)d_in[9];
    const float* Wih_r  = (const float*)d_in[10];
    const float* Whh_r  = (const float*)d_in[11];
    const float* bih_r  = (const float*)d_in[12];
    const float* bhh_r  = (const float*)d_in[13];
    const float* W_c    = (const float*)d_in[14];
    const float* b_c    = (const float*)d_in[15];
    float* out = (float*)d_out;

    // workspace map (bytes), total 59,506,688 (< proven 67.9MB)
    char* base = (char*)d_ws;
    f16* cb[3];
    cb[0] = (f16*)(base);                    // chunk buf: hi 8,388,608 B + lo 8,388,608 B
    cb[1] = (f16*)(base + 16777216);
    cb[2] = (f16*)(base + 33554432);
    f16* ws_s_hi = (f16*)(base + 50331648);  // 1,572,864 each
    f16* ws_s_lo = (f16*)(base + 51904512);
    f16* ws_r_hi = (f16*)(base + 53477376);
    f16* ws_r_lo = (f16*)(base + 55050240);
    float* wihT_s = (float*)(base + 56623104); // 786,432 each
    float* wihT_r = (float*)(base + 57409536);
    int* words   = (int*)(base + 58195968);    // 655,360
    int* eff     = (int*)(base + 58851328);    // 655,360

    const size_t LOFF = 4194304;  // f16 elements per half (8,388,608 B)
    #define HI(b) (b)
    #define LO(b) ((b) + LOFF)

    const dim3 blk(256);
    const dim3 gFus(CHM / 128, 512 / 64);
    const dim3 gArg(CHM / 64);

    // ---- weight prep ----
    wsplit_kernel<<<dim3(384), blk, 0, stream>>>(Whh_s, ws_s_hi, ws_s_lo);
    wsplit_kernel<<<dim3(384), blk, 0, stream>>>(Whh_r, ws_r_hi, ws_r_lo);
    wihT_kernel<<<dim3(768), blk, 0, stream>>>(Wih_s, wihT_s);
    wihT_kernel<<<dim3(768), blk, 0, stream>>>(Wih_r, wihT_r);

    // ---- h0 into chunk buffers 0,1 ----
    h0_kernel<<<gFus, blk, 0, stream>>>(x, W_in, b_in, HI(cb[0]), LO(cb[0]));
    h0_kernel<<<gFus, blk, 0, stream>>>(x + (size_t)CHM * 272, W_in, b_in, HI(cb[1]), LO(cb[1]));
    int c0 = 0, c1 = 1, fr = 2;

    // ---- sender: 10 fused GRU steps + argmax ----
    for (int t = 0; t < NT; ++t) {
        const int* wprev = (t == 0) ? (const int*)nullptr : (words + (size_t)(t - 1) * NB);
        fused_gru<0><<<gFus, blk, 0, stream>>>(
            HI(cb[c0]), LO(cb[c0]), HI(cb[fr]), LO(cb[fr]),
            ws_s_hi, ws_s_lo, wihT_s, bih_s, bhh_s, wprev);
        fused_gru<0><<<gFus, blk, 0, stream>>>(
            HI(cb[c1]), LO(cb[c1]), HI(cb[c0]), LO(cb[c0]),
            ws_s_hi, ws_s_lo, wihT_s, bih_s, bhh_s, wprev ? wprev + CHM : (const int*)nullptr);
        const int nf = c1; c1 = c0; c0 = fr; fr = nf;   // rotate
        argmax_split<<<gArg, blk, 0, stream>>>(
            HI(cb[c0]), LO(cb[c0]), W_sp, b_sp,
            gumbel + (size_t)t * NB * 128, words + (size_t)t * NB);
        argmax_split<<<gArg, blk, 0, stream>>>(
            HI(cb[c1]), LO(cb[c1]), W_sp, b_sp,
            gumbel + (size_t)t * NB * 128 + (size_t)CHM * 128, words + (size_t)t * NB + CHM);
    }
    eff_kernel<<<dim3(NB / 256), blk, 0, stream>>>(words, eff);

    // ---- receiver: 10 fused GRU steps (t=0 from zero state) ----
    for (int t = 0; t < NT; ++t) {
        const int* ef = eff + (size_t)t * NB;
        if (t == 0) {
            fused_gru<1><<<gFus, blk, 0, stream>>>(
                HI(cb[c0]), LO(cb[c0]), HI(cb[fr]), LO(cb[fr]),
                ws_r_hi, ws_r_lo, wihT_r, bih_r, bhh_r, ef);
            fused_gru<1><<<gFus, blk, 0, stream>>>(
                HI(cb[c1]), LO(cb[c1]), HI(cb[c0]), LO(cb[c0]),
                ws_r_hi, ws_r_lo, wihT_r, bih_r, bhh_r, ef + CHM);
        } else {
            fused_gru<0><<<gFus, blk, 0, stream>>>(
                HI(cb[c0]), LO(cb[c0]), HI(cb[fr]), LO(cb[fr]),
                ws_r_hi, ws_r_lo, wihT_r, bih_r, bhh_r, ef);
            fused_gru<0><<<gFus, blk, 0, stream>>>(
                HI(cb[c1]), LO(cb[c1]), HI(cb[c0]), LO(cb[c0]),
                ws_r_hi, ws_r_lo, wihT_r, bih_r, bhh_r, ef + CHM);
        }
        const int nf = c1; c1 = c0; c0 = fr; fr = nf;   // rotate
    }

    // ---- score ----
    score_kernel<<<dim3(CHM / 256), blk, 0, stream>>>(
        HI(cb[c0]), LO(cb[c0]), x, W_c, b_c, out);
    score_kernel<<<dim3(CHM / 256), blk, 0, stream>>>(
        HI(cb[c1]), LO(cb[c1]), x + (size_t)CHM * 272, W_c, b_c, out + (size_t)CHM * 10);
}